// Round 8
// baseline (1225.329 us; speedup 1.0000x reference)
//
#include <hip/hip_runtime.h>
#include <cmath>
#include <cstdint>

namespace {

constexpr int kLevels = 12;      // MAX_LEVELS=12 -> levels >= 12 always masked out
constexpr unsigned kNB = 32768;  // 32^3 Morton buckets
constexpr unsigned kCap = 520;   // entries (float2) in the per-wave tile arena

typedef float f32x4 __attribute__((ext_vector_type(4)));
typedef float f32x4u __attribute__((ext_vector_type(4), aligned(8)));

struct LevelMeta { float scale; unsigned res; unsigned size; unsigned off; };
struct Meta { LevelMeta lv[kLevels]; };

__device__ inline unsigned spread5(unsigned v) {
  v &= 31u;
  v = (v | (v << 8)) & 0x0000100Fu;
  v = (v | (v << 4)) & 0x000010C3u;
  v = (v | (v << 2)) & 0x00001249u;
  return v;
}

__device__ inline unsigned bucket_of(float x, float y, float z) {
  unsigned xi = (unsigned)fminf(fmaxf(x * 32.0f, 0.0f), 31.0f);
  unsigned yi = (unsigned)fminf(fmaxf(y * 32.0f, 0.0f), 31.0f);
  unsigned zi = (unsigned)fminf(fmaxf(z * 32.0f, 0.0f), 31.0f);
  return spread5(xi) | (spread5(yi) << 1) | (spread5(zi) << 2);
}

}  // namespace

// ---------------- sort prefix ----------------

__global__ __launch_bounds__(256) void k_hist(const float* __restrict__ xyz,
                                              unsigned* __restrict__ counts, int n) {
  const int i = blockIdx.x * blockDim.x + threadIdx.x;
  if (i >= n) return;
  atomicAdd(&counts[bucket_of(xyz[3 * i], xyz[3 * i + 1], xyz[3 * i + 2])], 1u);
}

__global__ __launch_bounds__(1024) void k_scan(const unsigned* __restrict__ counts,
                                               unsigned* __restrict__ cursor) {
  __shared__ unsigned part[1024];
  const int t = threadIdx.x;
  const int base = t * 32;
  unsigned loc[32];
  unsigned run = 0;
#pragma unroll
  for (int j = 0; j < 32; ++j) { loc[j] = run; run += counts[base + j]; }
  part[t] = run;
  __syncthreads();
  for (int off = 1; off < 1024; off <<= 1) {
    unsigned v = (t >= off) ? part[t - off] : 0u;
    __syncthreads();
    part[t] += v;
    __syncthreads();
  }
  const unsigned ebase = part[t] - run;
#pragma unroll
  for (int j = 0; j < 32; ++j) cursor[base + j] = ebase + loc[j];
}

__global__ __launch_bounds__(256) void k_scatter(const float* __restrict__ xyz,
                                                 unsigned* __restrict__ cursor,
                                                 f32x4* __restrict__ sorted, int n) {
  const int i = blockIdx.x * blockDim.x + threadIdx.x;
  if (i >= n) return;
  const float x = xyz[3 * i], y = xyz[3 * i + 1], z = xyz[3 * i + 2];
  const unsigned pos = atomicAdd(&cursor[bucket_of(x, y, z)], 1u);
  f32x4 v;
  v.x = x; v.y = y; v.z = z; v.w = __uint_as_float((unsigned)i);
  sorted[pos] = v;
}

// ---------------- main: pipelined wave-cooperative LDS tiles ----------------

__global__ __launch_bounds__(256) void k_main_sorted(
    const f32x4* __restrict__ sorted,
    const float* __restrict__ txy,
    const float* __restrict__ tyz,
    const float* __restrict__ txz,
    const int* __restrict__ step_ptr,
    float* __restrict__ out,
    int n, Meta meta)
{
  // per-wave 8320B region: first 4160B = ONE tile arena (520 float2) during
  // the loop (ISSUE never touches LDS; a wave's DS ops execute in order ->
  // sequential arena reuse is safe); afterwards the region is reused as
  // [8 x 260 float] output staging. All wave-local: no __syncthreads.
  __shared__ float smem[4][2080];
  __shared__ unsigned idxs[256];

  const int tid = threadIdx.x;
  const int wid = tid >> 6;
  const int lane = tid & 63;
  const int g = blockIdx.x * 256 + tid;
  const bool valid = g < n;
  const f32x4 s = sorted[valid ? g : (n - 1)];
  idxs[tid] = valid ? __float_as_uint(s.w) : 0xFFFFFFFFu;

  const int step = *step_ptr;
  int level = step / 1000 + 1;
  level = level > kLevels ? kLevels : level;
  const int active = 2 * level;

  // wave bbox (all 64 lanes hold a valid point; tail lanes clamp to n-1)
  float mnx = s.x, mxx = s.x, mny = s.y, mxy = s.y, mnz = s.z, mxz = s.z;
#pragma unroll
  for (int m = 1; m < 64; m <<= 1) {
    mnx = fminf(mnx, __shfl_xor(mnx, m)); mxx = fmaxf(mxx, __shfl_xor(mxx, m));
    mny = fminf(mny, __shfl_xor(mny, m)); mxy = fmaxf(mxy, __shfl_xor(mxy, m));
    mnz = fminf(mnz, __shfl_xor(mnz, m)); mxz = fmaxf(mxz, __shfl_xor(mxz, m));
  }

  const float cA[3] = {s.x, s.y, s.x};
  const float cB[3] = {s.y, s.z, s.z};
  const float loA[3] = {mnx, mny, mnx}, hiA[3] = {mxx, mxy, mxx};
  const float loB[3] = {mny, mnz, mnz}, hiB[3] = {mxy, mxz, mxz};
  const float2* tabs[3] = {reinterpret_cast<const float2*>(txy),
                           reinterpret_cast<const float2*>(tyz),
                           reinterpret_cast<const float2*>(txz)};

  float2* arena = reinterpret_cast<float2*>(&smem[wid][0]);

  float acc[2 * kLevels];
#pragma unroll
  for (int k = 0; k < 2 * kLevels; ++k) acc[k] = 0.0f;

  // pipeline register state: depth-2 prefetch REQUIRES 3 banks
  // (ISSUE(u+2), live u+1, CONSUME(u) are pairwise distinct mod 3).
  float2 pv[3][8];
  unsigned pI[3], pkk[3], pS[3], pC[3], pR[3], pX0[3], pY0[3], pT[3];

  // ISSUE: compute tile geometry (wave-uniform -> SGPR) and launch the
  // global loads for unit u into register bank u%3. No LDS touched here.
  auto ISSUE = [&](int u) {
    const int l = u / 3, p = u % 3, b = u % 3;
    const LevelMeta lm = meta.lv[l];
    const float2* __restrict__ tab = tabs[p] + lm.off;

    const unsigned tx0 = (unsigned)floorf(fmaf(loA[p], lm.scale, 0.5f));
    const unsigned tx1 = (unsigned)floorf(fmaf(hiA[p], lm.scale, 0.5f));
    const unsigned ty0 = (unsigned)floorf(fmaf(loB[p], lm.scale, 0.5f));
    const unsigned ty1 = (unsigned)floorf(fmaf(hiB[p], lm.scale, 0.5f));
    const unsigned C = tx1 - tx0 + 2u;
    const unsigned R = ty1 - ty0 + 2u;
    const unsigned kk0 = 32u - (unsigned)__builtin_clz(C - 1u);
    const unsigned rpi0 = 64u >> (kk0 > 6u ? 6u : kk0);
    const unsigned sI0 = (R + rpi0 - 1u) / rpi0;
    const unsigned tiled =
        (C <= 64u && R * (C | 1u) <= kCap && sI0 <= 8u) ? 1u : 0u;
    const unsigned sT = (unsigned)__builtin_amdgcn_readfirstlane((int)tiled);
    pT[b] = sT;

    if (sT) {
      const unsigned sC = (unsigned)__builtin_amdgcn_readfirstlane((int)C);
      const unsigned sR = (unsigned)__builtin_amdgcn_readfirstlane((int)R);
      const unsigned sX0 = (unsigned)__builtin_amdgcn_readfirstlane((int)tx0);
      const unsigned sY0 = (unsigned)__builtin_amdgcn_readfirstlane((int)ty0);
      const unsigned sI = (unsigned)__builtin_amdgcn_readfirstlane((int)sI0);
      const unsigned kk = 32u - (unsigned)__builtin_clz(sC - 1u);
      const unsigned rpi = 64u >> kk;
      pC[b] = sC; pR[b] = sR; pS[b] = sC | 1u; pkk[b] = kk; pI[b] = sI;
      pX0[b] = sX0; pY0[b] = sY0;
      const unsigned rr = lane >> kk;
      const unsigned cc = lane & ((1u << kk) - 1u);
#pragma unroll
      for (unsigned t = 0; t < 8; ++t) {
        if (t < sI) {  // scalar branch (sI uniform)
          unsigned gi = (sY0 + t * rpi + rr) * lm.res + sX0 + cc;
          if (gi >= lm.size) gi -= lm.size;  // per-entry wrap == ref's %
          // out-of-tile lanes may read junk (still inside the table
          // allocation); their arena writes are guarded in CONSUME
          pv[b][t] = tab[gi];
        }
      }
    } else {
      // fallback: per-lane paired divergent gathers (l=11 + Morton jumps)
      const float posx = fmaf(cA[p], lm.scale, 0.5f);
      const float posy = fmaf(cB[p], lm.scale, 0.5f);
      const unsigned ix = (unsigned)floorf(posx);
      const unsigned iy = (unsigned)floorf(posy);
      unsigned i00 = ix + iy * lm.res;          // < size always
      unsigned i01 = i00 + lm.res;              // < 2*size
      if (i01 >= lm.size) i01 -= lm.size;
      const f32x4 r0 = *reinterpret_cast<const f32x4u*>(tab + i00);
      const f32x4 r1 = *reinterpret_cast<const f32x4u*>(tab + i01);
      pv[b][0] = make_float2(r0.x, r0.y);
      pv[b][1] = make_float2(r0.z, r0.w);
      pv[b][2] = make_float2(r1.x, r1.y);
      pv[b][3] = make_float2(r1.z, r1.w);
    }
  };

  // CONSUME: ds_write bank u%3 -> arena, read 4 corners, interpolate.
  auto CONSUME = [&](int u) {
    const int l = u / 3, p = u % 3, b = u % 3;
    const LevelMeta lm = meta.lv[l];
    const float2* __restrict__ tab = tabs[p] + lm.off;

    const float posx = fmaf(cA[p], lm.scale, 0.5f);
    const float posy = fmaf(cB[p], lm.scale, 0.5f);
    const float g0x = floorf(posx), g0y = floorf(posy);
    const float fx = posx - g0x, fy = posy - g0y;
    const unsigned ix = (unsigned)g0x, iy = (unsigned)g0y;

    float2 q00, q01, q10, q11;
    if (pT[b]) {  // scalar branch
      const unsigned kk = pkk[b], sS = pS[b], sI = pI[b];
      const unsigned sC = pC[b], sR = pR[b];
      const unsigned rpi = 64u >> kk;
      const unsigned rr = lane >> kk;
      const unsigned cc = lane & ((1u << kk) - 1u);
#pragma unroll
      for (unsigned t = 0; t < 8; ++t) {
        if (t < sI) {
          const unsigned r = t * rpi + rr;
          if ((cc < sC) & (r < sR)) arena[r * sS + cc] = pv[b][t];
        }
      }
      const unsigned a = (iy - pY0[b]) * sS + (ix - pX0[b]);
      q00 = arena[a];
      q10 = arena[a + 1];
      q01 = arena[a + sS];
      q11 = arena[a + sS + 1];
    } else {
      unsigned i00 = ix + iy * lm.res;
      unsigned i01 = i00 + lm.res;
      if (i01 >= lm.size) i01 -= lm.size;
      const float2 tf = *tab;  // wrap target is entry 0
      q00 = pv[b][0];
      q10 = (i00 == lm.size - 1u) ? tf : pv[b][1];
      q01 = pv[b][2];
      q11 = (i01 == lm.size - 1u) ? tf : pv[b][3];
    }

    const float w00 = (1.0f - fx) * (1.0f - fy);
    const float w01 = (1.0f - fx) * fy;
    const float w10 = fx * (1.0f - fy);
    const float w11 = fx * fy;
    acc[2 * l + 0] += w00 * q00.x + w01 * q01.x + w10 * q10.x + w11 * q11.x;
    acc[2 * l + 1] += w00 * q00.y + w01 * q01.y + w10 * q10.y + w11 * q11.y;
  };

  ISSUE(0);
  ISSUE(1);
#pragma unroll
  for (int u = 0; u < 36; ++u) {
    if (u + 2 < 36) ISSUE(u + 2);
    CONSUME(u);
  }

  // static level mask
#pragma unroll
  for (int k = 0; k < 2 * kLevels; ++k)
    if (k >= active) acc[k] = 0.0f;

  // reuse smem region as output staging (wave-local, no barrier):
  // write 16B/lane, read back so each store covers 8 whole 128B output rows
  float* wlds = &smem[wid][0];
#pragma unroll
  for (int c = 0; c < 8; ++c) {
    f32x4 v;
    v.x = c < 6 ? acc[4 * c + 0] : 0.0f;
    v.y = c < 6 ? acc[4 * c + 1] : 0.0f;
    v.z = c < 6 ? acc[4 * c + 2] : 0.0f;
    v.w = c < 6 ? acc[4 * c + 3] : 0.0f;
    *reinterpret_cast<f32x4*>(wlds + c * 260 + lane * 4) = v;
  }
#pragma unroll
  for (int q = 0; q < 8; ++q) {
    const int p2 = q * 8 + (lane >> 3);  // point within wave
    const int c = lane & 7;              // 16B chunk within row
    const unsigned r = idxs[wid * 64 + p2];
    const f32x4 v = *reinterpret_cast<const f32x4*>(wlds + c * 260 + p2 * 4);
    if (r != 0xFFFFFFFFu)
      __builtin_nontemporal_store(v, reinterpret_cast<f32x4*>(out) + (size_t)r * 8 + c);
  }
}

// ---------------- fallback (no-sort) if ws too small ----------------

__global__ __launch_bounds__(256) void k_fused_linear(
    const float* __restrict__ xyz,
    const float* __restrict__ txy,
    const float* __restrict__ tyz,
    const float* __restrict__ txz,
    const int* __restrict__ step_ptr,
    float* __restrict__ out,
    int n, Meta meta)
{
  __shared__ float lds[4 * 2048];
  const int tid = threadIdx.x;
  const int wid = tid >> 6;
  const int lane = tid & 63;
  const int bbase = blockIdx.x * 256;
  const int i = bbase + tid;
  const int pi = i < n ? i : (n - 1);

  const int step = *step_ptr;
  int level = step / 1000 + 1;
  level = level > kLevels ? kLevels : level;
  const int active = 2 * level;

  const float px = xyz[3 * pi], py = xyz[3 * pi + 1], pz = xyz[3 * pi + 2];
  float acc[2 * kLevels];
#pragma unroll
  for (int k = 0; k < 2 * kLevels; ++k) acc[k] = 0.0f;

  auto do_plane = [&](float c0, float c1, const float* __restrict__ tabf) {
    const float2* __restrict__ tab = reinterpret_cast<const float2*>(tabf);
#pragma unroll
    for (int l = 0; l < kLevels; ++l) {
      const LevelMeta lm = meta.lv[l];
      const float2* tb = tab + lm.off;
      const float posx = fmaf(c0, lm.scale, 0.5f);
      const float posy = fmaf(c1, lm.scale, 0.5f);
      const float g0x = floorf(posx), g0y = floorf(posy);
      const float fx = posx - g0x, fy = posy - g0y;
      const unsigned ix = (unsigned)g0x, iy = (unsigned)g0y;
      unsigned i00 = ix + iy * lm.res;
      unsigned i01 = i00 + lm.res;
      if (i01 >= lm.size) i01 -= lm.size;
      const f32x4 r0 = *reinterpret_cast<const f32x4u*>(tb + i00);
      const f32x4 r1 = *reinterpret_cast<const f32x4u*>(tb + i01);
      const float2 tf = *tb;
      const bool w0 = (i00 == lm.size - 1u), w1 = (i01 == lm.size - 1u);
      const float t10x = w0 ? tf.x : r0.z, t10y = w0 ? tf.y : r0.w;
      const float t11x = w1 ? tf.x : r1.z, t11y = w1 ? tf.y : r1.w;
      const float w00 = (1.0f - fx) * (1.0f - fy);
      const float w01 = (1.0f - fx) * fy;
      const float w10 = fx * (1.0f - fy);
      const float w11 = fx * fy;
      acc[2 * l + 0] += w00 * r0.x + w01 * r1.x + w10 * t10x + w11 * t11x;
      acc[2 * l + 1] += w00 * r0.y + w01 * r1.y + w10 * t10y + w11 * t11y;
    }
  };
  do_plane(px, py, txy);
  do_plane(py, pz, tyz);
  do_plane(px, pz, txz);

#pragma unroll
  for (int k = 0; k < 2 * kLevels; ++k)
    if (k >= active) acc[k] = 0.0f;

  float* wlds = lds + wid * 2048;
#pragma unroll
  for (int c = 0; c < 8; ++c) {
    f32x4 v;
    v.x = c < 6 ? acc[4 * c + 0] : 0.0f;
    v.y = c < 6 ? acc[4 * c + 1] : 0.0f;
    v.z = c < 6 ? acc[4 * c + 2] : 0.0f;
    v.w = c < 6 ? acc[4 * c + 3] : 0.0f;
    *reinterpret_cast<f32x4*>(wlds + c * 256 + lane * 4) = v;
  }
  __syncthreads();

  const long long wbase = (long long)bbase + wid * 64;
  f32x4* obase = reinterpret_cast<f32x4*>(out) + wbase * 8;
#pragma unroll
  for (int q = 0; q < 8; ++q) {
    const int p = q * 8 + (lane >> 3);
    const int c = lane & 7;
    const f32x4 v = *reinterpret_cast<const f32x4*>(wlds + c * 256 + p * 4);
    if (wbase + p < n)
      __builtin_nontemporal_store(v, obase + q * 64 + lane);
  }
}

extern "C" void kernel_launch(void* const* d_in, const int* in_sizes, int n_in,
                              void* d_out, int out_size, void* d_ws, size_t ws_size,
                              hipStream_t stream) {
  const float* xyz = (const float*)d_in[0];
  const float* txy = (const float*)d_in[1];
  const float* tyz = (const float*)d_in[2];
  const float* txz = (const float*)d_in[3];
  const int* step  = (const int*)d_in[4];
  float* out = (float*)d_out;
  const int n = in_sizes[0] / 3;

  // Replicate _meta() in double precision (margins >= 0.0128 to every ceil
  // boundary -- far beyond any libm 1-ulp difference vs numpy).
  Meta meta;
  unsigned off = 0;
  const double pls = std::exp2(std::log2(2048.0 / 16.0) / 15.0);
  for (int l = 0; l < 16; ++l) {
    const double scale = 16.0 * std::pow(pls, (double)l) - 1.0;
    const unsigned res = (unsigned)std::ceil(scale) + 1u;
    unsigned long long params = (unsigned long long)res * (unsigned long long)res;
    if (params > (1ull << 19)) params = (1ull << 19);
    params = ((params + 7ull) / 8ull) * 8ull;
    if (l < kLevels) {
      meta.lv[l].scale = (float)scale;
      meta.lv[l].res = res;
      meta.lv[l].size = (unsigned)params;
      meta.lv[l].off = off;
    }
    off += (unsigned)params;
  }

  const dim3 block(256);
  const dim3 grid((unsigned)((n + 255) / 256));

  const size_t sorted_off = 256 * 1024;
  const size_t need = sorted_off + (size_t)n * sizeof(f32x4);

  if (ws_size >= need) {
    unsigned* counts = (unsigned*)d_ws;
    unsigned* cursor = counts + kNB;
    f32x4* sorted = (f32x4*)((char*)d_ws + sorted_off);

    hipMemsetAsync(counts, 0, kNB * sizeof(unsigned), stream);
    hipLaunchKernelGGL(k_hist, grid, block, 0, stream, xyz, counts, n);
    hipLaunchKernelGGL(k_scan, dim3(1), dim3(1024), 0, stream, counts, cursor);
    hipLaunchKernelGGL(k_scatter, grid, block, 0, stream, xyz, cursor, sorted, n);
    hipLaunchKernelGGL(k_main_sorted, grid, block, 0, stream,
                       sorted, txy, tyz, txz, step, out, n, meta);
  } else {
    hipLaunchKernelGGL(k_fused_linear, grid, block, 0, stream,
                       xyz, txy, tyz, txz, step, out, n, meta);
  }
}

// Round 9
// 1166.013 us; speedup vs baseline: 1.0509x; 1.0509x over previous
//
#include <hip/hip_runtime.h>
#include <cmath>
#include <cstdint>

namespace {

constexpr int kLevels = 12;      // MAX_LEVELS=12 -> levels >= 12 always masked out
constexpr unsigned kNB = 32768;  // 32^3 Morton buckets
constexpr unsigned kCapL = 346;  // float2 entries per plane-tile (3 tiles = 8304B/wave)

typedef float f32x4 __attribute__((ext_vector_type(4)));
typedef float f32x4u __attribute__((ext_vector_type(4), aligned(8)));

struct LevelMeta { float scale; unsigned res; unsigned size; unsigned off; };
struct Meta { LevelMeta lv[kLevels]; };

__device__ inline unsigned spread5(unsigned v) {
  v &= 31u;
  v = (v | (v << 8)) & 0x0000100Fu;
  v = (v | (v << 4)) & 0x000010C3u;
  v = (v | (v << 2)) & 0x00001249u;
  return v;
}

__device__ inline unsigned bucket_of(float x, float y, float z) {
  unsigned xi = (unsigned)fminf(fmaxf(x * 32.0f, 0.0f), 31.0f);
  unsigned yi = (unsigned)fminf(fmaxf(y * 32.0f, 0.0f), 31.0f);
  unsigned zi = (unsigned)fminf(fmaxf(z * 32.0f, 0.0f), 31.0f);
  return spread5(xi) | (spread5(yi) << 1) | (spread5(zi) << 2);
}

}  // namespace

// ---------------- sort prefix ----------------

__global__ __launch_bounds__(256) void k_hist(const float* __restrict__ xyz,
                                              unsigned* __restrict__ counts, int n) {
  const int i = blockIdx.x * blockDim.x + threadIdx.x;
  if (i >= n) return;
  atomicAdd(&counts[bucket_of(xyz[3 * i], xyz[3 * i + 1], xyz[3 * i + 2])], 1u);
}

__global__ __launch_bounds__(1024) void k_scan(const unsigned* __restrict__ counts,
                                               unsigned* __restrict__ cursor) {
  __shared__ unsigned part[1024];
  const int t = threadIdx.x;
  const int base = t * 32;
  unsigned loc[32];
  unsigned run = 0;
#pragma unroll
  for (int j = 0; j < 32; ++j) { loc[j] = run; run += counts[base + j]; }
  part[t] = run;
  __syncthreads();
  for (int off = 1; off < 1024; off <<= 1) {
    unsigned v = (t >= off) ? part[t - off] : 0u;
    __syncthreads();
    part[t] += v;
    __syncthreads();
  }
  const unsigned ebase = part[t] - run;
#pragma unroll
  for (int j = 0; j < 32; ++j) cursor[base + j] = ebase + loc[j];
}

__global__ __launch_bounds__(256) void k_scatter(const float* __restrict__ xyz,
                                                 unsigned* __restrict__ cursor,
                                                 f32x4* __restrict__ sorted, int n) {
  const int i = blockIdx.x * blockDim.x + threadIdx.x;
  if (i >= n) return;
  const float x = xyz[3 * i], y = xyz[3 * i + 1], z = xyz[3 * i + 2];
  const unsigned pos = atomicAdd(&cursor[bucket_of(x, y, z)], 1u);
  f32x4 v;
  v.x = x; v.y = y; v.z = z; v.w = __uint_as_float((unsigned)i);
  sorted[pos] = v;
}

// ---------------- main: level-batched wave-cooperative LDS tiles ----------------
// Per level, all 3 planes' tile loads are issued before any consumption ->
// ONE global-latency drain covers 3 (level,plane) units (vs 1 unit in R6).
// No cross-iteration register banks (R8's failure); pv[] liveness is one
// iteration, so the register allocator reuses it and occupancy recovers.

__global__ __launch_bounds__(256) void k_main_sorted(
    const f32x4* __restrict__ sorted,
    const float* __restrict__ txy,
    const float* __restrict__ tyz,
    const float* __restrict__ txz,
    const int* __restrict__ step_ptr,
    float* __restrict__ out,
    int n, Meta meta)
{
  // per-wave 8320B region: 3 plane-tiles (346 float2 each, 8304B) during the
  // loop; reused afterwards as [8 x 260 float] output staging. A wave's DS ops
  // execute in order -> sequential reuse is safe, no __syncthreads anywhere.
  __shared__ float smem[4][2080];
  __shared__ unsigned idxs[256];

  const int tid = threadIdx.x;
  const int wid = tid >> 6;
  const int lane = tid & 63;
  const int g = blockIdx.x * 256 + tid;
  const bool valid = g < n;
  const f32x4 s = sorted[valid ? g : (n - 1)];
  idxs[tid] = valid ? __float_as_uint(s.w) : 0xFFFFFFFFu;

  const int step = *step_ptr;
  int level = step / 1000 + 1;
  level = level > kLevels ? kLevels : level;
  const int active = 2 * level;

  // wave bbox (all 64 lanes hold a valid point; tail lanes clamp to n-1)
  float mnx = s.x, mxx = s.x, mny = s.y, mxy = s.y, mnz = s.z, mxz = s.z;
#pragma unroll
  for (int m = 1; m < 64; m <<= 1) {
    mnx = fminf(mnx, __shfl_xor(mnx, m)); mxx = fmaxf(mxx, __shfl_xor(mxx, m));
    mny = fminf(mny, __shfl_xor(mny, m)); mxy = fmaxf(mxy, __shfl_xor(mxy, m));
    mnz = fminf(mnz, __shfl_xor(mnz, m)); mxz = fmaxf(mxz, __shfl_xor(mxz, m));
  }

  const float cA[3] = {s.x, s.y, s.x};
  const float cB[3] = {s.y, s.z, s.z};
  const float loA[3] = {mnx, mny, mnx}, hiA[3] = {mxx, mxy, mxx};
  const float loB[3] = {mny, mnz, mnz}, hiB[3] = {mxy, mxz, mxz};
  const float2* tabs[3] = {reinterpret_cast<const float2*>(txy),
                           reinterpret_cast<const float2*>(tyz),
                           reinterpret_cast<const float2*>(txz)};

  float2* arena = reinterpret_cast<float2*>(&smem[wid][0]);

  float acc[2 * kLevels];
#pragma unroll
  for (int k = 0; k < 2 * kLevels; ++k) acc[k] = 0.0f;

#pragma unroll
  for (int l = 0; l < kLevels; ++l) {
    const LevelMeta lm = meta.lv[l];

    // per-plane state, live only within this level iteration
    float2 pv[3][8];
    unsigned pS[3], pX0[3], pY0[3], pT[3], pI[3], pkk[3], pC[3], pR[3];

    // ---- Phase A: geometry + issue ALL 3 planes' loads (no LDS here) ----
#pragma unroll
    for (int p = 0; p < 3; ++p) {
      const float2* __restrict__ tab = tabs[p] + lm.off;

      const unsigned tx0 = (unsigned)floorf(fmaf(loA[p], lm.scale, 0.5f));
      const unsigned tx1 = (unsigned)floorf(fmaf(hiA[p], lm.scale, 0.5f));
      const unsigned ty0 = (unsigned)floorf(fmaf(loB[p], lm.scale, 0.5f));
      const unsigned ty1 = (unsigned)floorf(fmaf(hiB[p], lm.scale, 0.5f));
      const unsigned C = tx1 - tx0 + 2u;
      const unsigned R = ty1 - ty0 + 2u;
      const unsigned kk0 = 32u - (unsigned)__builtin_clz(C - 1u);
      const unsigned rpi0 = 64u >> (kk0 > 6u ? 6u : kk0);
      const unsigned sI0 = (R + rpi0 - 1u) / rpi0;
      const unsigned tiled =
          (C <= 64u && R * (C | 1u) <= kCapL && sI0 <= 8u) ? 1u : 0u;
      const unsigned sT = (unsigned)__builtin_amdgcn_readfirstlane((int)tiled);
      pT[p] = sT;

      if (sT) {
        const unsigned sC = (unsigned)__builtin_amdgcn_readfirstlane((int)C);
        const unsigned sR = (unsigned)__builtin_amdgcn_readfirstlane((int)R);
        const unsigned sX0 = (unsigned)__builtin_amdgcn_readfirstlane((int)tx0);
        const unsigned sY0 = (unsigned)__builtin_amdgcn_readfirstlane((int)ty0);
        const unsigned sI = (unsigned)__builtin_amdgcn_readfirstlane((int)sI0);
        const unsigned kk = 32u - (unsigned)__builtin_clz(sC - 1u);
        const unsigned rpi = 64u >> kk;
        pC[p] = sC; pR[p] = sR; pS[p] = sC | 1u; pkk[p] = kk; pI[p] = sI;
        pX0[p] = sX0; pY0[p] = sY0;
        const unsigned rr = lane >> kk;
        const unsigned cc = lane & ((1u << kk) - 1u);
#pragma unroll
        for (unsigned t = 0; t < 8; ++t) {
          if (t < sI) {  // scalar branch (sI uniform)
            unsigned gi = (sY0 + t * rpi + rr) * lm.res + sX0 + cc;
            if (gi >= lm.size) gi -= lm.size;  // per-entry wrap == ref's %
            pv[p][t] = tab[gi];  // junk lanes read in-bounds junk; write guarded
          }
        }
      } else {
        // fallback: per-lane paired divergent gathers (l=11 + Morton jumps)
        const float posx = fmaf(cA[p], lm.scale, 0.5f);
        const float posy = fmaf(cB[p], lm.scale, 0.5f);
        const unsigned ix = (unsigned)floorf(posx);
        const unsigned iy = (unsigned)floorf(posy);
        unsigned i00 = ix + iy * lm.res;          // < size always
        unsigned i01 = i00 + lm.res;              // < 2*size
        if (i01 >= lm.size) i01 -= lm.size;
        const f32x4 r0 = *reinterpret_cast<const f32x4u*>(tab + i00);
        const f32x4 r1 = *reinterpret_cast<const f32x4u*>(tab + i01);
        pv[p][0] = make_float2(r0.x, r0.y);
        pv[p][1] = make_float2(r0.z, r0.w);
        pv[p][2] = make_float2(r1.x, r1.y);
        pv[p][3] = make_float2(r1.z, r1.w);
      }
    }

    // ---- Phase B/C: per plane, ds_write tile -> corner reads -> bilinear ----
#pragma unroll
    for (int p = 0; p < 3; ++p) {
      const float2* __restrict__ tab = tabs[p] + lm.off;
      float2* tile = arena + p * kCapL;

      const float posx = fmaf(cA[p], lm.scale, 0.5f);
      const float posy = fmaf(cB[p], lm.scale, 0.5f);
      const float g0x = floorf(posx), g0y = floorf(posy);
      const float fx = posx - g0x, fy = posy - g0y;
      const unsigned ix = (unsigned)g0x, iy = (unsigned)g0y;

      float2 q00, q01, q10, q11;
      if (pT[p]) {  // scalar branch
        const unsigned kk = pkk[p], sS = pS[p], sI = pI[p];
        const unsigned sC = pC[p], sR = pR[p];
        const unsigned rpi = 64u >> kk;
        const unsigned rr = lane >> kk;
        const unsigned cc = lane & ((1u << kk) - 1u);
#pragma unroll
        for (unsigned t = 0; t < 8; ++t) {
          if (t < sI) {
            const unsigned r = t * rpi + rr;
            if ((cc < sC) & (r < sR)) tile[r * sS + cc] = pv[p][t];
          }
        }
        const unsigned a = (iy - pY0[p]) * sS + (ix - pX0[p]);
        q00 = tile[a];
        q10 = tile[a + 1];
        q01 = tile[a + sS];
        q11 = tile[a + sS + 1];
      } else {
        unsigned i00 = ix + iy * lm.res;
        unsigned i01 = i00 + lm.res;
        if (i01 >= lm.size) i01 -= lm.size;
        const float2 tf = *tab;  // wrap target is entry 0
        q00 = pv[p][0];
        q10 = (i00 == lm.size - 1u) ? tf : pv[p][1];
        q01 = pv[p][2];
        q11 = (i01 == lm.size - 1u) ? tf : pv[p][3];
      }

      const float w00 = (1.0f - fx) * (1.0f - fy);
      const float w01 = (1.0f - fx) * fy;
      const float w10 = fx * (1.0f - fy);
      const float w11 = fx * fy;
      acc[2 * l + 0] += w00 * q00.x + w01 * q01.x + w10 * q10.x + w11 * q11.x;
      acc[2 * l + 1] += w00 * q00.y + w01 * q01.y + w10 * q10.y + w11 * q11.y;
    }
  }

  // static level mask
#pragma unroll
  for (int k = 0; k < 2 * kLevels; ++k)
    if (k >= active) acc[k] = 0.0f;

  // reuse smem region as output staging (wave-local, no barrier):
  // write 16B/lane, read back so each store covers 8 whole 128B output rows
  float* wlds = &smem[wid][0];
#pragma unroll
  for (int c = 0; c < 8; ++c) {
    f32x4 v;
    v.x = c < 6 ? acc[4 * c + 0] : 0.0f;
    v.y = c < 6 ? acc[4 * c + 1] : 0.0f;
    v.z = c < 6 ? acc[4 * c + 2] : 0.0f;
    v.w = c < 6 ? acc[4 * c + 3] : 0.0f;
    *reinterpret_cast<f32x4*>(wlds + c * 260 + lane * 4) = v;
  }
#pragma unroll
  for (int q = 0; q < 8; ++q) {
    const int p2 = q * 8 + (lane >> 3);  // point within wave
    const int c = lane & 7;              // 16B chunk within row
    const unsigned r = idxs[wid * 64 + p2];
    const f32x4 v = *reinterpret_cast<const f32x4*>(wlds + c * 260 + p2 * 4);
    if (r != 0xFFFFFFFFu)
      __builtin_nontemporal_store(v, reinterpret_cast<f32x4*>(out) + (size_t)r * 8 + c);
  }
}

// ---------------- fallback (no-sort) if ws too small ----------------

__global__ __launch_bounds__(256) void k_fused_linear(
    const float* __restrict__ xyz,
    const float* __restrict__ txy,
    const float* __restrict__ tyz,
    const float* __restrict__ txz,
    const int* __restrict__ step_ptr,
    float* __restrict__ out,
    int n, Meta meta)
{
  __shared__ float lds[4 * 2048];
  const int tid = threadIdx.x;
  const int wid = tid >> 6;
  const int lane = tid & 63;
  const int bbase = blockIdx.x * 256;
  const int i = bbase + tid;
  const int pi = i < n ? i : (n - 1);

  const int step = *step_ptr;
  int level = step / 1000 + 1;
  level = level > kLevels ? kLevels : level;
  const int active = 2 * level;

  const float px = xyz[3 * pi], py = xyz[3 * pi + 1], pz = xyz[3 * pi + 2];
  float acc[2 * kLevels];
#pragma unroll
  for (int k = 0; k < 2 * kLevels; ++k) acc[k] = 0.0f;

  auto do_plane = [&](float c0, float c1, const float* __restrict__ tabf) {
    const float2* __restrict__ tab = reinterpret_cast<const float2*>(tabf);
#pragma unroll
    for (int l = 0; l < kLevels; ++l) {
      const LevelMeta lm = meta.lv[l];
      const float2* tb = tab + lm.off;
      const float posx = fmaf(c0, lm.scale, 0.5f);
      const float posy = fmaf(c1, lm.scale, 0.5f);
      const float g0x = floorf(posx), g0y = floorf(posy);
      const float fx = posx - g0x, fy = posy - g0y;
      const unsigned ix = (unsigned)g0x, iy = (unsigned)g0y;
      unsigned i00 = ix + iy * lm.res;
      unsigned i01 = i00 + lm.res;
      if (i01 >= lm.size) i01 -= lm.size;
      const f32x4 r0 = *reinterpret_cast<const f32x4u*>(tb + i00);
      const f32x4 r1 = *reinterpret_cast<const f32x4u*>(tb + i01);
      const float2 tf = *tb;
      const bool w0 = (i00 == lm.size - 1u), w1 = (i01 == lm.size - 1u);
      const float t10x = w0 ? tf.x : r0.z, t10y = w0 ? tf.y : r0.w;
      const float t11x = w1 ? tf.x : r1.z, t11y = w1 ? tf.y : r1.w;
      const float w00 = (1.0f - fx) * (1.0f - fy);
      const float w01 = (1.0f - fx) * fy;
      const float w10 = fx * (1.0f - fy);
      const float w11 = fx * fy;
      acc[2 * l + 0] += w00 * r0.x + w01 * r1.x + w10 * t10x + w11 * t11x;
      acc[2 * l + 1] += w00 * r0.y + w01 * r1.y + w10 * t10y + w11 * t11y;
    }
  };
  do_plane(px, py, txy);
  do_plane(py, pz, tyz);
  do_plane(px, pz, txz);

#pragma unroll
  for (int k = 0; k < 2 * kLevels; ++k)
    if (k >= active) acc[k] = 0.0f;

  float* wlds = lds + wid * 2048;
#pragma unroll
  for (int c = 0; c < 8; ++c) {
    f32x4 v;
    v.x = c < 6 ? acc[4 * c + 0] : 0.0f;
    v.y = c < 6 ? acc[4 * c + 1] : 0.0f;
    v.z = c < 6 ? acc[4 * c + 2] : 0.0f;
    v.w = c < 6 ? acc[4 * c + 3] : 0.0f;
    *reinterpret_cast<f32x4*>(wlds + c * 256 + lane * 4) = v;
  }
  __syncthreads();

  const long long wbase = (long long)bbase + wid * 64;
  f32x4* obase = reinterpret_cast<f32x4*>(out) + wbase * 8;
#pragma unroll
  for (int q = 0; q < 8; ++q) {
    const int p = q * 8 + (lane >> 3);
    const int c = lane & 7;
    const f32x4 v = *reinterpret_cast<const f32x4*>(wlds + c * 256 + p * 4);
    if (wbase + p < n)
      __builtin_nontemporal_store(v, obase + q * 64 + lane);
  }
}

extern "C" void kernel_launch(void* const* d_in, const int* in_sizes, int n_in,
                              void* d_out, int out_size, void* d_ws, size_t ws_size,
                              hipStream_t stream) {
  const float* xyz = (const float*)d_in[0];
  const float* txy = (const float*)d_in[1];
  const float* tyz = (const float*)d_in[2];
  const float* txz = (const float*)d_in[3];
  const int* step  = (const int*)d_in[4];
  float* out = (float*)d_out;
  const int n = in_sizes[0] / 3;

  // Replicate _meta() in double precision (margins >= 0.0128 to every ceil
  // boundary -- far beyond any libm 1-ulp difference vs numpy).
  Meta meta;
  unsigned off = 0;
  const double pls = std::exp2(std::log2(2048.0 / 16.0) / 15.0);
  for (int l = 0; l < 16; ++l) {
    const double scale = 16.0 * std::pow(pls, (double)l) - 1.0;
    const unsigned res = (unsigned)std::ceil(scale) + 1u;
    unsigned long long params = (unsigned long long)res * (unsigned long long)res;
    if (params > (1ull << 19)) params = (1ull << 19);
    params = ((params + 7ull) / 8ull) * 8ull;
    if (l < kLevels) {
      meta.lv[l].scale = (float)scale;
      meta.lv[l].res = res;
      meta.lv[l].size = (unsigned)params;
      meta.lv[l].off = off;
    }
    off += (unsigned)params;
  }

  const dim3 block(256);
  const dim3 grid((unsigned)((n + 255) / 256));

  const size_t sorted_off = 256 * 1024;
  const size_t need = sorted_off + (size_t)n * sizeof(f32x4);

  if (ws_size >= need) {
    unsigned* counts = (unsigned*)d_ws;
    unsigned* cursor = counts + kNB;
    f32x4* sorted = (f32x4*)((char*)d_ws + sorted_off);

    hipMemsetAsync(counts, 0, kNB * sizeof(unsigned), stream);
    hipLaunchKernelGGL(k_hist, grid, block, 0, stream, xyz, counts, n);
    hipLaunchKernelGGL(k_scan, dim3(1), dim3(1024), 0, stream, counts, cursor);
    hipLaunchKernelGGL(k_scatter, grid, block, 0, stream, xyz, cursor, sorted, n);
    hipLaunchKernelGGL(k_main_sorted, grid, block, 0, stream,
                       sorted, txy, tyz, txz, step, out, n, meta);
  } else {
    hipLaunchKernelGGL(k_fused_linear, grid, block, 0, stream,
                       xyz, txy, tyz, txz, step, out, n, meta);
  }
}